// Round 1
// baseline (1004.052 us; speedup 1.0000x reference)
//
#include <hip/hip_runtime.h>
#include <cstdint>

// ---------------------------------------------------------------------------
// PerceiverResampler on MI355X (gfx950) — round 1: correctness-first bf16 MFMA
// B=32 SEQ=512 DIM=1024 DEPTH=6 HEADS=8 DHEAD=64 INNER=512 NLAT=64
// ---------------------------------------------------------------------------

#define DEVINL __device__ __forceinline__

typedef __attribute__((ext_vector_type(8))) short short8_t;   // 8 x bf16 (4 VGPR)
typedef __attribute__((ext_vector_type(4))) float f32x4;      // MFMA acc

DEVINL ushort f2bf(float f) {          // RNE f32 -> bf16 (finite inputs)
  union { float f; uint32_t u; } c; c.f = f;
  uint32_t u = c.u;
  u += ((u >> 16) & 1u) + 0x7fffu;
  return (ushort)(u >> 16);
}
DEVINL float bf2f(ushort u) {
  union { uint32_t u; float f; } c; c.u = ((uint32_t)u) << 16;
  return c.f;
}
DEVINL f32x4 mfma16(short8_t a, short8_t b, f32x4 c) {
  // A: row = lane&15, k = (lane>>4)*8 + i ; B: col = lane&15, same k
  // D: col = lane&15, row = (lane>>4)*4 + r   [guide-verified C/D layout]
  return __builtin_amdgcn_mfma_f32_16x16x32_bf16(a, b, c, 0, 0, 0);
}

// ---------------------------------------------------------------------------
// Fold + transpose weights: outT[l][c][r] = bf16( W[l][r][c] * g[l][r] * scale )
// W: [DEPTH][R][C] f32, g: [DEPTH][R] or null, outT: [DEPTH][C][R] bf16
// grid (C/32, R/32, DEPTH), block 256
__global__ __launch_bounds__(256) void k_fold_T(const float* __restrict__ W,
    const float* __restrict__ g, float scale, ushort* __restrict__ outT,
    int R, int C) {
  __shared__ float tile[32][33];
  int l = blockIdx.z;
  const float* Wl = W + (size_t)l * R * C;
  const float* gl = g ? g + (size_t)l * R : nullptr;
  ushort* Ol = outT + (size_t)l * R * C;
  int r0 = blockIdx.y * 32, c0 = blockIdx.x * 32;
  int tx = threadIdx.x & 31, ty = threadIdx.x >> 5;   // ty 0..7
#pragma unroll
  for (int i = 0; i < 4; ++i) {
    int r = ty + i * 8;
    float gv = gl ? gl[r0 + r] : 1.0f;
    tile[r][tx] = Wl[(size_t)(r0 + r) * C + c0 + tx] * gv * scale;
  }
  __syncthreads();
#pragma unroll
  for (int i = 0; i < 4; ++i) {
    int jl = ty + i * 8;
    Ol[(size_t)(c0 + jl) * R + r0 + tx] = f2bf(tile[tx][jl]);
  }
}

// ---------------------------------------------------------------------------
// Bias rows: bkvm[l][c] = ln_media_b[l] . Wkv[l][:,c]   (c in [0,1024))
//            bkvl[l][c] = ln_lat_b[l]   . Wkv[l][:,c]
//            bq[l][c]   = 0.125 * ln_lat_b[l] . Wq[l][:,c] (c in [0,512))
// grid (40, DEPTH), block 256 (64 cols x 4 d-groups)
__global__ __launch_bounds__(256) void k_bias_rows(const float* __restrict__ Wkv,
    const float* __restrict__ Wq, const float* __restrict__ lnmb,
    const float* __restrict__ lnlb, float* __restrict__ bkvm,
    float* __restrict__ bkvl, float* __restrict__ bq) {
  __shared__ float red[4][64];
  int l = blockIdx.y;
  int c0 = blockIdx.x * 64;
  int tx = threadIdx.x & 63, dg = threadIdx.x >> 6;
  const float* Wsrc; const float* bv; int ld; int c; float scale = 1.0f; float* outp;
  if (c0 < 1024) {
    Wsrc = Wkv + (size_t)l * 1024 * 1024; bv = lnmb + l * 1024; ld = 1024;
    c = c0 + tx; outp = bkvm + l * 1024 + c;
  } else if (c0 < 2048) {
    Wsrc = Wkv + (size_t)l * 1024 * 1024; bv = lnlb + l * 1024; ld = 1024;
    c = c0 - 1024 + tx; outp = bkvl + l * 1024 + (c0 - 1024 + tx);
  } else {
    Wsrc = Wq + (size_t)l * 1024 * 512; bv = lnlb + l * 1024; ld = 512;
    c = c0 - 2048 + tx; outp = bq + l * 512 + (c0 - 2048 + tx); scale = 0.125f;
  }
  float acc = 0.f;
  for (int d = dg * 256; d < dg * 256 + 256; ++d)
    acc += bv[d] * Wsrc[(size_t)d * ld + c];
  red[dg][tx] = acc;
  __syncthreads();
  if (dg == 0) *outp = (red[0][tx] + red[1][tx] + red[2][tx] + red[3][tx]) * scale;
}

// ---------------------------------------------------------------------------
// Row layernorm (no affine) -> bf16. Optional pos add (indexed row&511).
// grid nrows, block 256 (4 f32/thread)
__global__ __launch_bounds__(256) void k_rownorm(const float* __restrict__ in,
    const float* __restrict__ pos, ushort* __restrict__ out) {
  int row = blockIdx.x, t = threadIdx.x;
  float4 v = *(const float4*)(in + (size_t)row * 1024 + t * 4);
  if (pos) {
    float4 p = *(const float4*)(pos + (size_t)(row & 511) * 1024 + t * 4);
    v.x += p.x; v.y += p.y; v.z += p.z; v.w += p.w;
  }
  float s = v.x + v.y + v.z + v.w;
  float q = v.x * v.x + v.y * v.y + v.z * v.z + v.w * v.w;
#pragma unroll
  for (int off = 32; off; off >>= 1) { s += __shfl_xor(s, off); q += __shfl_xor(q, off); }
  __shared__ float rs[4], rq[4];
  if ((t & 63) == 0) { rs[t >> 6] = s; rq[t >> 6] = q; }
  __syncthreads();
  s = rs[0] + rs[1] + rs[2] + rs[3];
  q = rq[0] + rq[1] + rq[2] + rq[3];
  float mean = s * (1.0f / 1024.0f);
  float var = q * (1.0f / 1024.0f) - mean * mean;
  float rstd = rsqrtf(var + 1e-5f);
  ushort4 o;
  o.x = f2bf((v.x - mean) * rstd);
  o.y = f2bf((v.y - mean) * rstd);
  o.z = f2bf((v.z - mean) * rstd);
  o.w = f2bf((v.w - mean) * rstd);
  *(ushort4*)(out + (size_t)row * 1024 + t * 4) = o;
}

// Final layernorm with affine -> f32 out. grid 2048, block 256.
__global__ __launch_bounds__(256) void k_finalln(const float* __restrict__ in,
    const float* __restrict__ g, const float* __restrict__ b, float* __restrict__ out) {
  int row = blockIdx.x, t = threadIdx.x;
  float4 v = *(const float4*)(in + (size_t)row * 1024 + t * 4);
  float s = v.x + v.y + v.z + v.w;
  float q = v.x * v.x + v.y * v.y + v.z * v.z + v.w * v.w;
#pragma unroll
  for (int off = 32; off; off >>= 1) { s += __shfl_xor(s, off); q += __shfl_xor(q, off); }
  __shared__ float rs[4], rq[4];
  if ((t & 63) == 0) { rs[t >> 6] = s; rq[t >> 6] = q; }
  __syncthreads();
  s = rs[0] + rs[1] + rs[2] + rs[3];
  q = rq[0] + rq[1] + rq[2] + rq[3];
  float mean = s * (1.0f / 1024.0f);
  float var = q * (1.0f / 1024.0f) - mean * mean;
  float rstd = rsqrtf(var + 1e-5f);
  float4 g4 = *(const float4*)(g + t * 4);
  float4 b4 = *(const float4*)(b + t * 4);
  float4 o;
  o.x = (v.x - mean) * rstd * g4.x + b4.x;
  o.y = (v.y - mean) * rstd * g4.y + b4.y;
  o.z = (v.z - mean) * rstd * g4.z + b4.z;
  o.w = (v.w - mean) * rstd * g4.w + b4.w;
  *(float4*)(out + (size_t)row * 1024 + t * 4) = o;
}

// lat init: broadcast latents over batch. grid 2048, block 256.
__global__ __launch_bounds__(256) void k_latinit(const float* __restrict__ latents,
                                                 float* __restrict__ lat) {
  int row = blockIdx.x, t = threadIdx.x;
  *(float4*)(lat + (size_t)row * 1024 + t * 4) =
      *(const float4*)(latents + (size_t)(row & 63) * 1024 + t * 4);
}

// ---------------------------------------------------------------------------
// GEMM: C[M,N] = A[M,K](bf16,row-major) @ Bt[N,K]^T (bf16) + bias[N]
// 64x64 block tile, 4 waves (2x2 of 32x32), BK=32, single-buffered LDS.
// MODE 0: store bf16 to outA[row*N+col]
// MODE 1: KV split: b=row>>rowshift, jr=jbase+(row&mask);
//         col<512 -> outA[((b*576+jr)<<9)+col] ; else outB[... + col-512]
// MODE 2: outF[row*N+col] += v   (residual accumulate, f32)
template <int MODE>
__global__ __launch_bounds__(256) void k_gemm64(const ushort* __restrict__ A,
    const ushort* __restrict__ Bt, const float* __restrict__ bias,
    ushort* __restrict__ outA, ushort* __restrict__ outB, float* __restrict__ outF,
    int M, int N, int K, int rowshift, int jbase) {
  __shared__ ushort Al[64][40];
  __shared__ ushort Bl[64][40];
  int tid = threadIdx.x;
  int lane = tid & 63, w = tid >> 6, wr = w >> 1, wc = w & 1;
  int m0 = blockIdx.y * 64, n0 = blockIdx.x * 64;
  f32x4 acc[2][2] = {};
  int sr = tid >> 2, sc = (tid & 3) * 8;
  const ushort* Arow = A + (size_t)(m0 + sr) * K + sc;
  const ushort* Brow = Bt + (size_t)(n0 + sr) * K + sc;
  for (int k0 = 0; k0 < K; k0 += 32) {
    short8_t av = *(const short8_t*)(Arow + k0);
    short8_t bv = *(const short8_t*)(Brow + k0);
    __syncthreads();
    *(short8_t*)&Al[sr][sc] = av;
    *(short8_t*)&Bl[sr][sc] = bv;
    __syncthreads();
    short8_t a0 = *(const short8_t*)&Al[wr * 32 + (lane & 15)][(lane >> 4) << 3];
    short8_t a1 = *(const short8_t*)&Al[wr * 32 + 16 + (lane & 15)][(lane >> 4) << 3];
    short8_t b0 = *(const short8_t*)&Bl[wc * 32 + (lane & 15)][(lane >> 4) << 3];
    short8_t b1 = *(const short8_t*)&Bl[wc * 32 + 16 + (lane & 15)][(lane >> 4) << 3];
    acc[0][0] = mfma16(a0, b0, acc[0][0]);
    acc[0][1] = mfma16(a0, b1, acc[0][1]);
    acc[1][0] = mfma16(a1, b0, acc[1][0]);
    acc[1][1] = mfma16(a1, b1, acc[1][1]);
  }
#pragma unroll
  for (int mt = 0; mt < 2; ++mt)
#pragma unroll
    for (int nt = 0; nt < 2; ++nt)
#pragma unroll
      for (int r = 0; r < 4; ++r) {
        int row = m0 + wr * 32 + mt * 16 + ((lane >> 4) << 2) + r;
        int col = n0 + wc * 32 + nt * 16 + (lane & 15);
        float v = acc[mt][nt][r] + (bias ? bias[col] : 0.0f);
        if constexpr (MODE == 0) {
          outA[(size_t)row * N + col] = f2bf(v);
        } else if constexpr (MODE == 1) {
          int b = row >> rowshift;
          int jr = jbase + (row & ((1 << rowshift) - 1));
          size_t base = ((size_t)(b * 576 + jr)) << 9;
          if (col < 512) outA[base + col] = f2bf(v);
          else           outB[base + col - 512] = f2bf(v);
        } else {
          outF[(size_t)row * N + col] += v;
        }
      }
}

// ---------------------------------------------------------------------------
// Fused attention, one block per (b, h, half-of-32-rows). 256 thr = 4 waves.
// Wave (wr,wc): rows 16*wr..+15 (local), cols split by wc.
// S(bf16) kept in LDS [32][584]; V transposed per tile through kt.
__global__ __launch_bounds__(256) void k_attn(const ushort* __restrict__ Q,
    const ushort* __restrict__ Kb, const ushort* __restrict__ Vb,
    const int* __restrict__ amask, ushort* __restrict__ AO) {
  __shared__ ushort sim[32][584];
  __shared__ ushort kt[64][72];
  int blk = blockIdx.x;
  int half = blk & 1, h = (blk >> 1) & 7, b = blk >> 4;
  int tid = threadIdx.x, lane = tid & 63, w = tid >> 6;
  int wr = w >> 1, wc = w & 1;
  // Q fragments (16 rows of this wave, k = 0..63)
  short8_t aq0, aq1;
  {
    int qi = half * 32 + wr * 16 + (lane & 15);
    const ushort* qp = Q + ((size_t)(b * 64 + qi) << 9) + h * 64 + ((lane >> 4) << 3);
    aq0 = *(const short8_t*)qp;
    aq1 = *(const short8_t*)(qp + 32);
  }
  int sr = tid >> 2, scol = (tid & 3) << 4;
  // ---- phase 1: S = Q @ K^T -> sim (bf16)
  for (int jt = 0; jt < 9; ++jt) {
    const ushort* kp = Kb + ((size_t)(b * 576 + jt * 64 + sr) << 9) + h * 64 + scol;
    short8_t k0 = *(const short8_t*)kp;
    short8_t k1 = *(const short8_t*)(kp + 8);
    __syncthreads();                    // prior tile's MFMA reads complete
    *(short8_t*)&kt[sr][scol] = k0;
    *(short8_t*)&kt[sr][scol + 8] = k1;
    __syncthreads();
#pragma unroll
    for (int c2 = 0; c2 < 2; ++c2) {
      int ct = wc * 2 + c2;
      f32x4 acc = {};
      short8_t bk0 = *(const short8_t*)&kt[ct * 16 + (lane & 15)][(lane >> 4) << 3];
      short8_t bk1 = *(const short8_t*)&kt[ct * 16 + (lane & 15)][32 + ((lane >> 4) << 3)];
      acc = mfma16(aq0, bk0, acc);
      acc = mfma16(aq1, bk1, acc);
#pragma unroll
      for (int r = 0; r < 4; ++r)
        sim[wr * 16 + ((lane >> 4) << 2) + r][jt * 64 + ct * 16 + (lane & 15)] =
            f2bf(acc[r]);
    }
  }
  __syncthreads();
  // ---- phase 2: masked softmax per row (wave-parallel, 8 rows/wave)
  unsigned mbits = 0;
#pragma unroll
  for (int c = 1; c < 9; ++c)
    if (amask[b * 512 + (c - 1) * 64 + lane]) mbits |= (1u << c);
  for (int rr = 0; rr < 8; ++rr) {
    int row = w * 8 + rr;
    float vals[9];
    float m = -3.0e38f;
#pragma unroll
    for (int c = 0; c < 9; ++c) {
      float v = bf2f(sim[row][c * 64 + lane]);
      vals[c] = v;
      if (!((mbits >> c) & 1)) m = fmaxf(m, v);
    }
#pragma unroll
    for (int off = 32; off; off >>= 1) m = fmaxf(m, __shfl_xor(m, off));
    float ssum = 0.f;
    float p[9];
#pragma unroll
    for (int c = 0; c < 9; ++c) {
      p[c] = ((mbits >> c) & 1) ? 0.f : __expf(vals[c] - m);
      ssum += p[c];
    }
#pragma unroll
    for (int off = 32; off; off >>= 1) ssum += __shfl_xor(ssum, off);
    float inv = 1.0f / ssum;
#pragma unroll
    for (int c = 0; c < 9; ++c)
      sim[row][c * 64 + lane] = f2bf(p[c] * inv);
  }
  __syncthreads();
  // ---- phase 3: O = P @ V (V transposed through kt per tile)
  f32x4 oacc[2] = {};
  for (int jt = 0; jt < 9; ++jt) {
    const ushort* vp = Vb + ((size_t)(b * 576 + jt * 64 + sr) << 9) + h * 64 + scol;
    short8_t v0 = *(const short8_t*)vp;
    short8_t v1 = *(const short8_t*)(vp + 8);
    __syncthreads();                    // prior tile's MFMA reads complete
#pragma unroll
    for (int e = 0; e < 8; ++e) kt[scol + e][sr] = (ushort)v0[e];
#pragma unroll
    for (int e = 0; e < 8; ++e) kt[scol + 8 + e][sr] = (ushort)v1[e];
    __syncthreads();
#pragma unroll
    for (int d2 = 0; d2 < 2; ++d2) {
      int dt = wc * 2 + d2;
      short8_t pa0 = *(const short8_t*)&sim[wr * 16 + (lane & 15)][jt * 64 + ((lane >> 4) << 3)];
      short8_t pa1 = *(const short8_t*)&sim[wr * 16 + (lane & 15)][jt * 64 + 32 + ((lane >> 4) << 3)];
      short8_t bv0 = *(const short8_t*)&kt[dt * 16 + (lane & 15)][(lane >> 4) << 3];
      short8_t bv1 = *(const short8_t*)&kt[dt * 16 + (lane & 15)][32 + ((lane >> 4) << 3)];
      oacc[d2] = mfma16(pa0, bv0, oacc[d2]);
      oacc[d2] = mfma16(pa1, bv1, oacc[d2]);
    }
  }
#pragma unroll
  for (int d2 = 0; d2 < 2; ++d2) {
    int dt = wc * 2 + d2;
#pragma unroll
    for (int r = 0; r < 4; ++r) {
      int i = half * 32 + wr * 16 + ((lane >> 4) << 2) + r;
      int d = dt * 16 + (lane & 15);
      AO[((size_t)(b * 64 + i) << 9) + h * 64 + d] = f2bf(oacc[d2][r]);
    }
  }
}

// ---------------------------------------------------------------------------
extern "C" void kernel_launch(void* const* d_in, const int* in_sizes, int n_in,
                              void* d_out, int out_size, void* d_ws, size_t ws_size,
                              hipStream_t stream) {
  const float* x       = (const float*)d_in[0];
  const int*   amask   = (const int*)d_in[1];
  const float* latents = (const float*)d_in[2];
  const float* pos     = (const float*)d_in[3];
  const float* lnmg    = (const float*)d_in[4];
  const float* lnmb    = (const float*)d_in[5];
  const float* lnlg    = (const float*)d_in[6];
  const float* lnlb    = (const float*)d_in[7];
  const float* Wq      = (const float*)d_in[8];
  const float* Wkv     = (const float*)d_in[9];
  const float* Wout    = (const float*)d_in[10];
  const float* fg      = (const float*)d_in[11];
  const float* fb      = (const float*)d_in[12];
  float* out = (float*)d_out;
  char* ws = (char*)d_ws;

  // ws layout (bytes), 256-aligned, total ~120.1 MiB
  ushort* xhat  = (ushort*)(ws + 0);           // [16384][1024] bf16   32 MiB
  ushort* wkvmT = (ushort*)(ws + 33554432);    // [6][1024][1024] bf16 12 MiB
  ushort* wkvlT = (ushort*)(ws + 46137344);    // [6][1024][1024] bf16 12 MiB
  ushort* wqT   = (ushort*)(ws + 58720256);    // [6][512][1024]  bf16  6 MiB
  ushort* woutT = (ushort*)(ws + 65011712);    // [6][1024][512]  bf16  6 MiB
  float*  bkvm  = (float*)(ws + 71303168);     // [6][1024] f32
  float*  bkvl  = (float*)(ws + 71327744);     // [6][1024] f32
  float*  bq    = (float*)(ws + 71352320);     // [6][512]  f32
  float*  lat   = (float*)(ws + 71364608);     // [2048][1024] f32      8 MiB
  ushort* lhat  = (ushort*)(ws + 79753216);    // [2048][1024] bf16     4 MiB
  ushort* qbuf  = (ushort*)(ws + 83947520);    // [2048][512]  bf16     2 MiB
  ushort* Kbuf  = (ushort*)(ws + 86044672);    // [32][576][512] bf16  18 MiB
  ushort* Vbuf  = (ushort*)(ws + 104919040);   // [32][576][512] bf16  18 MiB
  ushort* aobuf = (ushort*)(ws + 123793408);   // [2048][512]  bf16     2 MiB

  dim3 B256(256);
  // --- preprocessing (per call; weights are inputs, no caching allowed)
  k_fold_T<<<dim3(32, 32, 6), B256, 0, stream>>>(Wkv, lnmg, 1.0f, wkvmT, 1024, 1024);
  k_fold_T<<<dim3(32, 32, 6), B256, 0, stream>>>(Wkv, lnlg, 1.0f, wkvlT, 1024, 1024);
  k_fold_T<<<dim3(16, 32, 6), B256, 0, stream>>>(Wq, lnlg, 0.125f, wqT, 1024, 512);
  k_fold_T<<<dim3(32, 16, 6), B256, 0, stream>>>(Wout, nullptr, 1.0f, woutT, 512, 1024);
  k_bias_rows<<<dim3(40, 6), B256, 0, stream>>>(Wkv, Wq, lnmb, lnlb, bkvm, bkvl, bq);
  k_rownorm<<<16384, B256, 0, stream>>>(x, pos, xhat);     // x̂ once (stats layer-indep)
  k_latinit<<<2048, B256, 0, stream>>>(latents, lat);

  for (int l = 0; l < 6; ++l) {
    k_rownorm<<<2048, B256, 0, stream>>>(lat, nullptr, lhat);
    // q = l̂at @ (0.125 g⊙Wq) + bq  -> bf16 [2048][512]
    k_gemm64<0><<<dim3(8, 32), B256, 0, stream>>>(
        lhat, wqT + (size_t)l * 524288, bq + l * 512, qbuf, nullptr, nullptr,
        2048, 512, 1024, 0, 0);
    // latent kv rows (j = 0..63)
    k_gemm64<1><<<dim3(16, 32), B256, 0, stream>>>(
        lhat, wkvlT + (size_t)l * 1048576, bkvl + l * 1024, Kbuf, Vbuf, nullptr,
        2048, 1024, 1024, 6, 0);
    // media kv rows (j = 64..575) — the dominant GEMM
    k_gemm64<1><<<dim3(16, 256), B256, 0, stream>>>(
        xhat, wkvmT + (size_t)l * 1048576, bkvm + l * 1024, Kbuf, Vbuf, nullptr,
        16384, 1024, 1024, 9, 64);
    k_attn<<<512, B256, 0, stream>>>(qbuf, Kbuf, Vbuf, amask, aobuf);
    // lat += attn_out @ Wout
    k_gemm64<2><<<dim3(16, 32), B256, 0, stream>>>(
        aobuf, woutT + (size_t)l * 524288, nullptr, nullptr, nullptr, lat,
        2048, 1024, 512, 0, 0);
  }
  k_finalln<<<2048, B256, 0, stream>>>(lat, fg, fb, out);
}